// Round 3
// baseline (502.473 us; speedup 1.0000x reference)
//
#include <hip/hip_runtime.h>
#include <math.h>

#define NBINS 15
#define NSLOTS 32
#define SLOT_STRIDE 48          // 45 used, padded
#define GRID 2048
#define BLOCK 256

typedef float v4f __attribute__((ext_vector_type(4)));

__device__ __forceinline__ float vmax4(v4f v) {
    return fmaxf(fmaxf(v.x, v.y), fmaxf(v.z, v.w));
}
__device__ __forceinline__ float vexpsum(v4f v) {
    return (__expf(v.x) + __expf(v.y)) + (__expf(v.z) + __expf(v.w));
}

// One wave = 8 rows (seg = lane>>3), each lane owns 16 contiguous columns.
// accuracy: label's logit selected IN-REGISTER (no reload), reduced as a
// third fmax chain; acc = (q == m). Main loads are non-temporal (read-once).
// Last block (ticket) folds the 32x45 partials and writes the final ECE.
__global__ __launch_bounds__(BLOCK) void ece_fused(
    const float* __restrict__ logits,
    const int*   __restrict__ labels,
    int n_groups,
    double*   __restrict__ g_part,    // [NSLOTS][SLOT_STRIDE]: cnt|sumc|suma
    unsigned* __restrict__ ticket,
    float*    __restrict__ out,
    double inv_n)
{
    __shared__ float    s_sumc[NBINS];
    __shared__ float    s_suma[NBINS];
    __shared__ unsigned s_cnt[NBINS];
    __shared__ unsigned s_old;
    __shared__ double   s_fin[3 * NBINS];

    const int tid = threadIdx.x;
    if (tid < NBINS) { s_sumc[tid] = 0.f; s_suma[tid] = 0.f; s_cnt[tid] = 0u; }
    __syncthreads();

    const int lane = tid & 63;
    const int seg  = lane >> 3;
    const int t    = lane & 7;
    const int wave_global = blockIdx.x * (BLOCK >> 6) + (tid >> 6);
    const int n_waves     = GRID * (BLOCK >> 6);

    for (int g = wave_global; g < n_groups; g += n_waves) {
        const int row = g * 8 + seg;
        const v4f* rp = reinterpret_cast<const v4f*>(
            logits + ((size_t)row << 7) + (t << 4));
        const v4f v0 = __builtin_nontemporal_load(rp);
        const v4f v1 = __builtin_nontemporal_load(rp + 1);
        const v4f v2 = __builtin_nontemporal_load(rp + 2);
        const v4f v3 = __builtin_nontemporal_load(rp + 3);
        const int lab = labels[row];

        // lane-local max over 16
        float m = fmaxf(fmaxf(vmax4(v0), vmax4(v1)), fmaxf(vmax4(v2), vmax4(v3)));
        // lane-local sum of exp(x) (independent chain; conf = exp(m)/p)
        float p = (vexpsum(v0) + vexpsum(v1)) + (vexpsum(v2) + vexpsum(v3));

        // in-register select of the label's logit (bit-exact copy)
        const int idx = lab & 15;
        const v4f ca  = (lab & 8) ? ((lab & 4) ? v3 : v2)
                                  : ((lab & 4) ? v1 : v0);
        const float s01 = (lab & 1) ? ca.y : ca.x;
        const float s23 = (lab & 1) ? ca.w : ca.z;
        const float xsel = (lab & 2) ? s23 : s01;
        (void)idx;
        float q = ((lab >> 4) == t) ? xsel : -INFINITY;

        // segmented 8-lane reductions (offsets stay in-segment)
        #pragma unroll
        for (int off = 4; off; off >>= 1) {
            m = fmaxf(m, __shfl_xor(m, off, 64));
            p += __shfl_xor(p, off, 64);
            q = fmaxf(q, __shfl_xor(q, off, 64));
        }

        if (t == 0) {
            const float conf = __expf(m) / p;              // = max softmax, <= 1
            const float acc  = (q == m) ? 1.0f : 0.0f;     // label logit is the max
            int bin = (int)ceilf(conf * 15.0f) - 1;        // bin k: (k/15,(k+1)/15]
            bin = bin < 0 ? 0 : (bin > NBINS - 1 ? NBINS - 1 : bin);
            atomicAdd(&s_cnt[bin], 1u);
            atomicAdd(&s_sumc[bin], conf);
            atomicAdd(&s_suma[bin], acc);
        }
    }

    __syncthreads();
    if (tid < 3 * NBINS) {
        const double val = (tid < NBINS)     ? (double)s_cnt[tid]
                         : (tid < 2 * NBINS) ? (double)s_sumc[tid - NBINS]
                                             : (double)s_suma[tid - 2 * NBINS];
        atomicAdd(&g_part[(size_t)(blockIdx.x & (NSLOTS - 1)) * SLOT_STRIDE + tid], val);
    }
    __threadfence();
    if (tid == 0) s_old = atomicAdd(ticket, 1u);
    __syncthreads();

    if (s_old == GRID - 1) {                 // last block: final reduction
        __threadfence();
        const int col = tid % 45;
        double acc = 0.0;
        if (tid < 225) {
            for (int k = tid / 45; k < NSLOTS; k += 5)
                acc += __hip_atomic_load(&g_part[(size_t)k * SLOT_STRIDE + col],
                                         __ATOMIC_RELAXED, __HIP_MEMORY_SCOPE_AGENT);
        }
        if (tid < 3 * NBINS) s_fin[tid] = 0.0;
        __syncthreads();
        if (tid < 225) atomicAdd(&s_fin[col], acc);
        __syncthreads();
        if (tid == 0) {
            double e = 0.0;
            for (int b = 0; b < NBINS; ++b) {
                const double c = s_fin[b];
                if (c > 0.0)
                    e += fabs(s_fin[NBINS + b] / c - s_fin[2 * NBINS + b] / c) * (c * inv_n);
            }
            out[0] = (float)e;
        }
    }
}

extern "C" void kernel_launch(void* const* d_in, const int* in_sizes, int n_in,
                              void* d_out, int out_size, void* d_ws, size_t ws_size,
                              hipStream_t stream) {
    const float* logits = (const float*)d_in[0];
    const int*   labels = (const int*)d_in[1];
    const int n_rows = in_sizes[1];            // 1048576 (divisible by 8)

    double*   g_part = (double*)d_ws;
    unsigned* ticket = (unsigned*)((char*)d_ws + (size_t)NSLOTS * SLOT_STRIDE * sizeof(double));

    hipMemsetAsync(d_ws, 0,
                   (size_t)NSLOTS * SLOT_STRIDE * sizeof(double) + sizeof(unsigned),
                   stream);

    const int n_groups = n_rows >> 3;
    ece_fused<<<GRID, BLOCK, 0, stream>>>(logits, labels, n_groups,
                                          g_part, ticket, (float*)d_out,
                                          1.0 / (double)n_rows);
}

// Round 4
// 422.157 us; speedup vs baseline: 1.1903x; 1.1903x over previous
//
#include <hip/hip_runtime.h>
#include <math.h>

#define NBINS 15
#define NSLOTS 32
#define SLOT_STRIDE 48          // 45 used, padded
#define GRID 2048
#define BLOCK 256

typedef float v4f __attribute__((ext_vector_type(4)));

__device__ __forceinline__ float vmax4(v4f v) {
    return fmaxf(fmaxf(v.x, v.y), fmaxf(v.z, v.w));
}
__device__ __forceinline__ float vexpsum(v4f v) {
    return (__expf(v.x) + __expf(v.y)) + (__expf(v.z) + __expf(v.w));
}

// One wave = 8 rows (seg = lane>>3), each lane owns 16 contiguous columns.
// accuracy: label's logit selected IN-REGISTER (no reload), reduced as a
// third fmax chain; acc = (q == m). PLAIN loads (nt regressed 5x: bypasses
// L2 path, 598 GB/s vs 6.6 TB/s).
// Last block (ticket) folds the 32x45 partials and writes the final ECE.
__global__ __launch_bounds__(BLOCK) void ece_fused(
    const float* __restrict__ logits,
    const int*   __restrict__ labels,
    int n_groups,
    double*   __restrict__ g_part,    // [NSLOTS][SLOT_STRIDE]: cnt|sumc|suma
    unsigned* __restrict__ ticket,
    float*    __restrict__ out,
    double inv_n)
{
    __shared__ float    s_sumc[NBINS];
    __shared__ float    s_suma[NBINS];
    __shared__ unsigned s_cnt[NBINS];
    __shared__ unsigned s_old;
    __shared__ double   s_fin[3 * NBINS];

    const int tid = threadIdx.x;
    if (tid < NBINS) { s_sumc[tid] = 0.f; s_suma[tid] = 0.f; s_cnt[tid] = 0u; }
    __syncthreads();

    const int lane = tid & 63;
    const int seg  = lane >> 3;
    const int t    = lane & 7;
    const int wave_global = blockIdx.x * (BLOCK >> 6) + (tid >> 6);
    const int n_waves     = GRID * (BLOCK >> 6);

    for (int g = wave_global; g < n_groups; g += n_waves) {
        const int row = g * 8 + seg;
        const v4f* rp = reinterpret_cast<const v4f*>(
            logits + ((size_t)row << 7) + (t << 4));
        const v4f v0 = rp[0];
        const v4f v1 = rp[1];
        const v4f v2 = rp[2];
        const v4f v3 = rp[3];
        const int lab = labels[row];

        // lane-local max over 16
        float m = fmaxf(fmaxf(vmax4(v0), vmax4(v1)), fmaxf(vmax4(v2), vmax4(v3)));
        // lane-local sum of exp(x) (independent chain; conf = exp(m)/p)
        float p = (vexpsum(v0) + vexpsum(v1)) + (vexpsum(v2) + vexpsum(v3));

        // in-register select of the label's logit (bit-exact copy)
        const v4f ca  = (lab & 8) ? ((lab & 4) ? v3 : v2)
                                  : ((lab & 4) ? v1 : v0);
        const float s01 = (lab & 1) ? ca.y : ca.x;
        const float s23 = (lab & 1) ? ca.w : ca.z;
        const float xsel = (lab & 2) ? s23 : s01;
        float q = ((lab >> 4) == t) ? xsel : -INFINITY;

        // segmented 8-lane reductions (offsets stay in-segment)
        #pragma unroll
        for (int off = 4; off; off >>= 1) {
            m = fmaxf(m, __shfl_xor(m, off, 64));
            p += __shfl_xor(p, off, 64);
            q = fmaxf(q, __shfl_xor(q, off, 64));
        }

        if (t == 0) {
            const float conf = __expf(m) / p;              // = max softmax, <= 1
            const float acc  = (q == m) ? 1.0f : 0.0f;     // label logit is the max
            int bin = (int)ceilf(conf * 15.0f) - 1;        // bin k: (k/15,(k+1)/15]
            bin = bin < 0 ? 0 : (bin > NBINS - 1 ? NBINS - 1 : bin);
            atomicAdd(&s_cnt[bin], 1u);
            atomicAdd(&s_sumc[bin], conf);
            atomicAdd(&s_suma[bin], acc);
        }
    }

    __syncthreads();
    if (tid < 3 * NBINS) {
        const double val = (tid < NBINS)     ? (double)s_cnt[tid]
                         : (tid < 2 * NBINS) ? (double)s_sumc[tid - NBINS]
                                             : (double)s_suma[tid - 2 * NBINS];
        atomicAdd(&g_part[(size_t)(blockIdx.x & (NSLOTS - 1)) * SLOT_STRIDE + tid], val);
    }
    __threadfence();
    if (tid == 0) s_old = atomicAdd(ticket, 1u);
    __syncthreads();

    if (s_old == GRID - 1) {                 // last block: final reduction
        __threadfence();
        const int col = tid % 45;
        double acc = 0.0;
        if (tid < 225) {
            for (int k = tid / 45; k < NSLOTS; k += 5)
                acc += __hip_atomic_load(&g_part[(size_t)k * SLOT_STRIDE + col],
                                         __ATOMIC_RELAXED, __HIP_MEMORY_SCOPE_AGENT);
        }
        if (tid < 3 * NBINS) s_fin[tid] = 0.0;
        __syncthreads();
        if (tid < 225) atomicAdd(&s_fin[col], acc);
        __syncthreads();
        if (tid == 0) {
            double e = 0.0;
            for (int b = 0; b < NBINS; ++b) {
                const double c = s_fin[b];
                if (c > 0.0)
                    e += fabs(s_fin[NBINS + b] / c - s_fin[2 * NBINS + b] / c) * (c * inv_n);
            }
            out[0] = (float)e;
        }
    }
}

extern "C" void kernel_launch(void* const* d_in, const int* in_sizes, int n_in,
                              void* d_out, int out_size, void* d_ws, size_t ws_size,
                              hipStream_t stream) {
    const float* logits = (const float*)d_in[0];
    const int*   labels = (const int*)d_in[1];
    const int n_rows = in_sizes[1];            // 1048576 (divisible by 8)

    double*   g_part = (double*)d_ws;
    unsigned* ticket = (unsigned*)((char*)d_ws + (size_t)NSLOTS * SLOT_STRIDE * sizeof(double));

    hipMemsetAsync(d_ws, 0,
                   (size_t)NSLOTS * SLOT_STRIDE * sizeof(double) + sizeof(unsigned),
                   stream);

    const int n_groups = n_rows >> 3;
    ece_fused<<<GRID, BLOCK, 0, stream>>>(logits, labels, n_groups,
                                          g_part, ticket, (float*)d_out,
                                          1.0 / (double)n_rows);
}

// Round 5
// 101.039 us; speedup vs baseline: 4.9731x; 4.1782x over previous
//
#include <hip/hip_runtime.h>
#include <math.h>

#define NBINS 15
#define NSLOTS 32   // partial-accumulator slots to spread global atomic contention

// One wave handles EIGHT rows: segment s = lane>>3 owns row group*8+s,
// lane t = lane&7 owns 16 contiguous columns (4x float4 loads).
// Segmented reductions use xor-shuffles with offsets 4,2,1 (stay in-segment).
// accuracy = (logits[row][label] == rowmax)  -- no argmax tracking needed.
// conf = exp(m) / sum(exp(x)): exps are independent of the max-reduce chain.
// NOTE: known-good round-2 baseline (101 us). Round-3/4 fusion experiment
// (__threadfence + ticket last-block reduction) regressed 4-5x: per-wave
// device-scope release fences thrash L2 for the whole dispatch. Do NOT fuse.
__global__ __launch_bounds__(256) void ece_main(
    const float* __restrict__ logits,
    const int*   __restrict__ labels,
    int n_groups,                      // n_rows / 8
    double* __restrict__ g_part)       // [NSLOTS][3*NBINS]: cnt | sumc | suma
{
    __shared__ float    s_sumc[NBINS];
    __shared__ float    s_suma[NBINS];
    __shared__ unsigned s_cnt[NBINS];

    const int tid = threadIdx.x;
    if (tid < NBINS) { s_sumc[tid] = 0.f; s_suma[tid] = 0.f; s_cnt[tid] = 0u; }
    __syncthreads();

    const int lane = tid & 63;
    const int seg  = lane >> 3;        // row within the 8-row group
    const int t    = lane & 7;         // 16-column chunk within the row
    const int wave_global = blockIdx.x * (blockDim.x >> 6) + (tid >> 6);
    const int n_waves     = gridDim.x * (blockDim.x >> 6);

    for (int g = wave_global; g < n_groups; g += n_waves) {
        const int row = g * 8 + seg;
        const float* rp = logits + ((size_t)row << 7) + (t << 4);
        const float4 v0 = *reinterpret_cast<const float4*>(rp);
        const float4 v1 = *reinterpret_cast<const float4*>(rp + 4);
        const float4 v2 = *reinterpret_cast<const float4*>(rp + 8);
        const float4 v3 = *reinterpret_cast<const float4*>(rp + 12);
        const int lab = labels[row];                       // 8 addrs, 32B span

        // lane-local max over 16 (tree)
        float a0 = fmaxf(fmaxf(v0.x, v0.y), fmaxf(v0.z, v0.w));
        float a1 = fmaxf(fmaxf(v1.x, v1.y), fmaxf(v1.z, v1.w));
        float a2 = fmaxf(fmaxf(v2.x, v2.y), fmaxf(v2.z, v2.w));
        float a3 = fmaxf(fmaxf(v3.x, v3.y), fmaxf(v3.z, v3.w));
        float m  = fmaxf(fmaxf(a0, a1), fmaxf(a2, a3));

        // lane-local sum of exp(x) (independent of m -> parallel dep chains)
        float e0 = __expf(v0.x) + __expf(v0.y) + __expf(v0.z) + __expf(v0.w);
        float e1 = __expf(v1.x) + __expf(v1.y) + __expf(v1.z) + __expf(v1.w);
        float e2 = __expf(v2.x) + __expf(v2.y) + __expf(v2.z) + __expf(v2.w);
        float e3 = __expf(v3.x) + __expf(v3.y) + __expf(v3.z) + __expf(v3.w);
        float p  = (e0 + e1) + (e2 + e3);

        // the label's logit (L1/L2 hit: same lines the wave just fetched)
        const float vlab = logits[((size_t)row << 7) + lab];

        // segmented 8-lane reductions
        #pragma unroll
        for (int off = 4; off; off >>= 1) {
            m = fmaxf(m, __shfl_xor(m, off, 64));
            p += __shfl_xor(p, off, 64);
        }

        if (t == 0) {
            const float conf = __expf(m) / p;              // = max softmax
            const float acc  = (vlab == m) ? 1.0f : 0.0f;  // pred == label
            int bin = (int)ceilf(conf * 15.0f) - 1;        // bin k: (k/15,(k+1)/15]
            bin = bin < 0 ? 0 : (bin > NBINS - 1 ? NBINS - 1 : bin);
            atomicAdd(&s_cnt[bin], 1u);
            atomicAdd(&s_sumc[bin], conf);
            atomicAdd(&s_suma[bin], acc);
        }
    }

    __syncthreads();
    if (tid < 3 * NBINS) {
        double val = (tid < NBINS)     ? (double)s_cnt[tid]
                   : (tid < 2 * NBINS) ? (double)s_sumc[tid - NBINS]
                                       : (double)s_suma[tid - 2 * NBINS];
        atomicAdd(&g_part[(size_t)(blockIdx.x & (NSLOTS - 1)) * (3 * NBINS) + tid], val);
    }
}

__global__ void ece_final(const double* __restrict__ g_part,
                          float* __restrict__ out, double inv_n)
{
    __shared__ double s[3 * NBINS];
    const int t = threadIdx.x;
    if (t < 3 * NBINS) {
        double acc = 0.0;
        for (int k = 0; k < NSLOTS; ++k) acc += g_part[k * 3 * NBINS + t];
        s[t] = acc;
    }
    __syncthreads();
    if (t == 0) {
        double e = 0.0;
        for (int b = 0; b < NBINS; ++b) {
            const double c = s[b];
            if (c > 0.0)
                e += fabs(s[NBINS + b] / c - s[2 * NBINS + b] / c) * (c * inv_n);
        }
        out[0] = (float)e;
    }
}

extern "C" void kernel_launch(void* const* d_in, const int* in_sizes, int n_in,
                              void* d_out, int out_size, void* d_ws, size_t ws_size,
                              hipStream_t stream) {
    const float* logits = (const float*)d_in[0];
    const int*   labels = (const int*)d_in[1];
    const int n_rows = in_sizes[1];            // 1048576 (divisible by 8)

    double* g_part = (double*)d_ws;
    hipMemsetAsync(g_part, 0, (size_t)NSLOTS * 3 * NBINS * sizeof(double), stream);

    const int n_groups = n_rows >> 3;
    ece_main<<<2048, 256, 0, stream>>>(logits, labels, n_groups, g_part);
    ece_final<<<1, 64, 0, stream>>>(g_part, (float*)d_out, 1.0 / (double)n_rows);
}